// Round 7
// baseline (154.454 us; speedup 1.0000x reference)
//
#include <hip/hip_runtime.h>

// ---------------------------------------------------------------------------
// SAGE_DGL: 2-layer GraphSAGE (mean agg) forward on MI355X.
// Round 7 (on round-6 base):
//   - XCD-sliced CSR fill: block b only handles dst slice (b&7); csr lines
//     become single-XCD-private -> L2 write merging -> kills the 51MB
//     write amplification seen in round 6 (WRITE_SIZE 83MB, 64B/store).
//   - agg gather: 8-deep ILP main loop + 2-deep tail (was 4-deep/1-deep).
// Pipeline: memset -> megafuse -> agg1 -> gemm1 -> agg2 -> gemm2+lsm.
// ---------------------------------------------------------------------------

constexpr int D_IN  = 128;
constexpr int HID   = 256;
constexpr int OUT_D = 64;
constexpr int SIZE1 = 25000;
constexpr int SIZE2 = 5000;
constexpr int SLOTS = 80;    // max degree slots; Binom(800k,1/25k) max ~58
constexpr int NXCD  = 8;
constexpr int SLICE1 = (SIZE1 + NXCD - 1) / NXCD;  // 3125
constexpr int SLICE2 = (SIZE2 + NXCD - 1) / NXCD;  // 625
constexpr int ECH = 2048;    // edges per fill block (256 thr x 8)

using bf16x8 = __attribute__((ext_vector_type(8))) short;
using f32x4  = __attribute__((ext_vector_type(4))) float;

__device__ inline unsigned short f32_to_bf16_rne(float f) {
    unsigned u = __builtin_bit_cast(unsigned, f);
    u = (u + 0x7fffu + ((u >> 16) & 1u)) >> 16;
    return (unsigned short)u;
}
__device__ inline float bf16_lo(unsigned u) {
    return __builtin_bit_cast(float, u << 16);
}
__device__ inline float bf16_hi(unsigned u) {
    return __builtin_bit_cast(float, u & 0xffff0000u);
}
__device__ inline unsigned pack_bf16(float lo, float hi) {
    return (unsigned)f32_to_bf16_rne(lo) | ((unsigned)f32_to_bf16_rne(hi) << 16);
}
__device__ inline void add8(float* a, uint4 v) {
    a[0] += bf16_lo(v.x); a[1] += bf16_hi(v.x);
    a[2] += bf16_lo(v.y); a[3] += bf16_hi(v.y);
    a[4] += bf16_lo(v.z); a[5] += bf16_hi(v.z);
    a[6] += bf16_lo(v.w); a[7] += bf16_hi(v.w);
}

// ---------------------------------------------------------------------------
// Megafuse: block roles by blockIdx range.
//   [0,f1):  fill1, XCD-sliced — block handles dst in slice (b&7) only
//   [f1,f2): fill2, XCD-sliced
//   [f2,f3): convert x -> bf16 (2 float4 / thread)
//   [f3,..): convert weights -> transposed bf16, K-concat [self||neigh]
// ---------------------------------------------------------------------------
__global__ void megafuse(const int* __restrict__ es1, const int* __restrict__ ed1,
                         int E1, int* __restrict__ cnt1, int* __restrict__ csr1,
                         const int* __restrict__ es2, const int* __restrict__ ed2,
                         int E2, int* __restrict__ cnt2, int* __restrict__ csr2,
                         const float* __restrict__ x, unsigned* __restrict__ xb,
                         long n4,
                         const float* __restrict__ Ws1, const float* __restrict__ Wn1,
                         const float* __restrict__ Ws2, const float* __restrict__ Wn2,
                         unsigned short* __restrict__ Wt1,
                         unsigned short* __restrict__ Wt2,
                         int f1, int f2, int f3) {
    const int b = blockIdx.x;
    const int tid = threadIdx.x;
    if (b < f1) {                       // fill layer 1 (sliced)
        const int xcd = b & (NXCD - 1);
        const int base = (b >> 3) * ECH + tid;
#pragma unroll
        for (int j = 0; j < ECH / 256; ++j) {
            int e = base + j * 256;
            if (e < E1) {
                int d = ed1[e];
                if (d / SLICE1 == xcd) {
                    int pos = atomicAdd(&cnt1[d], 1);
                    if (pos < SLOTS) csr1[d * SLOTS + pos] = es1[e];
                }
            }
        }
    } else if (b < f2) {                // fill layer 2 (sliced)
        const int bb = b - f1;
        const int xcd = bb & (NXCD - 1);
        const int base = (bb >> 3) * ECH + tid;
#pragma unroll
        for (int j = 0; j < ECH / 256; ++j) {
            int e = base + j * 256;
            if (e < E2) {
                int d = ed2[e];
                if (d / SLICE2 == xcd) {
                    int pos = atomicAdd(&cnt2[d], 1);
                    if (pos < SLOTS) csr2[d * SLOTS + pos] = es2[e];
                }
            }
        }
    } else if (b < f3) {                // convert x -> bf16
        long i0 = (long)(b - f2) * 512 + tid;
#pragma unroll
        for (int j = 0; j < 2; ++j) {
            long i = i0 + j * 256;
            if (i < n4) {
                float4 v = reinterpret_cast<const float4*>(x)[i];
                uint2 o;
                o.x = pack_bf16(v.x, v.y);
                o.y = pack_bf16(v.z, v.w);
                reinterpret_cast<uint2*>(xb)[i] = o;
            }
        }
    } else {                            // convert weights
        int i = (b - f3) * 256 + tid;
        if (i < HID * (2 * D_IN)) {     // Wt1: 256 x 256
            int n = i >> 8, k = i & 255;
            float v = (k < D_IN) ? Ws1[k * HID + n] : Wn1[(k - D_IN) * HID + n];
            Wt1[i] = f32_to_bf16_rne(v);
        } else {
            int j = i - HID * (2 * D_IN);
            if (j < OUT_D * (2 * HID)) {  // Wt2: 64 x 512
                int n = j >> 9, k = j & 511;
                float v = (k < HID) ? Ws2[k * OUT_D + n] : Wn2[(k - HID) * OUT_D + n];
                Wt2[j] = f32_to_bf16_rne(v);
            }
        }
    }
}

// ---------------------------------------------------------------------------
// Pull-mode mean aggregation (bf16 in/out, fp32 acc). Wave per dst node.
// Fixed-slot CSR: row d occupies csr[d*SLOTS .. d*SLOTS+cnt[d]).
// 4 groups of 16 lanes; group g walks edges g, g+4, ...; 8 edges in flight
// (main), then 2-deep, then 1 (tail). Cross-group shfl reduce at the end.
// ---------------------------------------------------------------------------
template <int QPL>
__global__ void agg_pull2(const uint4* __restrict__ X4,
                          const int* __restrict__ csr,
                          const int* __restrict__ cnt,
                          uint4* __restrict__ mean4, int ndst) {
    constexpr int R4 = QPL * 16;
    const int wid = threadIdx.x >> 6;
    const int lane = threadIdx.x & 63;
    const int d = blockIdx.x * 4 + wid;
    if (d >= ndst) return;
    const int n = min(cnt[d], SLOTS);
    const int beg = d * SLOTS;
    const int end = beg + n;
    const int g = lane >> 4;
    const int c = lane & 15;

    float acc[QPL][8];
#pragma unroll
    for (int q = 0; q < QPL; ++q)
#pragma unroll
        for (int j = 0; j < 8; ++j) acc[q][j] = 0.0f;

    int e = beg + g;
    for (; e + 28 < end; e += 32) {      // 8-deep main
        int s[8];
#pragma unroll
        for (int t = 0; t < 8; ++t) s[t] = csr[e + 4 * t];
#pragma unroll
        for (int q = 0; q < QPL; ++q) {
            uint4 v[8];
#pragma unroll
            for (int t = 0; t < 8; ++t) v[t] = X4[(long)s[t] * R4 + q * 16 + c];
#pragma unroll
            for (int t = 0; t < 8; ++t) add8(acc[q], v[t]);
        }
    }
    for (; e + 4 < end; e += 8) {        // 2-deep tail
        int s0 = csr[e], s1 = csr[e + 4];
#pragma unroll
        for (int q = 0; q < QPL; ++q) {
            uint4 v0 = X4[(long)s0 * R4 + q * 16 + c];
            uint4 v1 = X4[(long)s1 * R4 + q * 16 + c];
            add8(acc[q], v0); add8(acc[q], v1);
        }
    }
    if (e < end) {                       // final edge
        long s0 = csr[e];
#pragma unroll
        for (int q = 0; q < QPL; ++q) {
            uint4 v0 = X4[s0 * R4 + q * 16 + c];
            add8(acc[q], v0);
        }
    }
#pragma unroll
    for (int q = 0; q < QPL; ++q)
#pragma unroll
        for (int j = 0; j < 8; ++j) {
            acc[q][j] += __shfl_xor(acc[q][j], 16);
            acc[q][j] += __shfl_xor(acc[q][j], 32);
        }
    if (g == 0) {
        const float inv = 1.0f / (float)max(n, 1);
#pragma unroll
        for (int q = 0; q < QPL; ++q) {
            uint4 o;
            o.x = pack_bf16(acc[q][0] * inv, acc[q][1] * inv);
            o.y = pack_bf16(acc[q][2] * inv, acc[q][3] * inv);
            o.z = pack_bf16(acc[q][4] * inv, acc[q][5] * inv);
            o.w = pack_bf16(acc[q][6] * inv, acc[q][7] * inv);
            mean4[(long)d * R4 + q * 16 + c] = o;
        }
    }
}

// ---------------------------------------------------------------------------
// Fused SAGE GEMM via MFMA (bf16 in, fp32 acc).
// C[i][n] = act(Aself[i][:]@Wt[n][0:KPH] + Amean[i][:]@Wt[n][KPH:2KPH] + b[n])
// 64x64 tile, 4 waves (2x2), wave does 32x32 via 2x2 16x16x32 frags.
// LDS XOR-swizzled for conflict-free ds_read_b128.
// LSM=true: fuse row log_softmax (BN=64 == full row) via LDS tile + shfl.
// ---------------------------------------------------------------------------
template <int KPH, bool RELU, bool OUT_BF16, bool LSM>
__global__ __launch_bounds__(256) void sage_gemm_mfma(
    const unsigned short* __restrict__ Aself,
    const unsigned short* __restrict__ Amean,
    const unsigned short* __restrict__ Wt,
    const float* __restrict__ bias,
    void* __restrict__ Cout, int M, int N) {
    constexpr int BM = 64, BN = 64;
    constexpr int ITERS = (BM * KPH) / (256 * 8);
    __shared__ unsigned short As[BM * KPH];
    __shared__ unsigned short Bs[BN * KPH];

    const int tid = threadIdx.x;
    const int wid = tid >> 6;
    const int lane = tid & 63;
    const int wm = wid >> 1, wn = wid & 1;
    const int rowBase = blockIdx.x * BM;
    const int colBase = blockIdx.y * BN;

    f32x4 acc[2][2];
#pragma unroll
    for (int a = 0; a < 2; ++a)
#pragma unroll
        for (int b = 0; b < 2; ++b)
#pragma unroll
            for (int j = 0; j < 4; ++j) acc[a][b][j] = 0.0f;

#pragma unroll
    for (int p = 0; p < 2; ++p) {
        const unsigned short* __restrict__ A = p ? Amean : Aself;
        __syncthreads();
#pragma unroll
        for (int it = 0; it < ITERS; ++it) {
            int flat = (it * 256 + tid) * 8;
            int r = flat / KPH, kc = flat % KPH;
            int gr = rowBase + r;
            if (gr >= M) gr = M - 1;
            uint4 v = *reinterpret_cast<const uint4*>(&A[(long)gr * KPH + kc]);
            int idx = (r * KPH + kc) ^ ((r & 7) << 3);
            *reinterpret_cast<uint4*>(&As[idx]) = v;
        }
#pragma unroll
        for (int it = 0; it < ITERS; ++it) {
            int flat = (it * 256 + tid) * 8;
            int r = flat / KPH, kc = flat % KPH;
            uint4 v = *reinterpret_cast<const uint4*>(
                &Wt[(long)(colBase + r) * (2 * KPH) + p * KPH + kc]);
            int idx = (r * KPH + kc) ^ ((r & 7) << 3);
            *reinterpret_cast<uint4*>(&Bs[idx]) = v;
        }
        __syncthreads();
#pragma unroll
        for (int kk = 0; kk < KPH / 32; ++kk) {
            bf16x8 a[2], b[2];
            const int kb = kk * 32 + 8 * (lane >> 4);
#pragma unroll
            for (int f = 0; f < 2; ++f) {
                int r = wm * 32 + f * 16 + (lane & 15);
                int ia = (r * KPH + kb) ^ ((r & 7) << 3);
                a[f] = *reinterpret_cast<const bf16x8*>(&As[ia]);
                int rn = wn * 32 + f * 16 + (lane & 15);
                int ib = (rn * KPH + kb) ^ ((rn & 7) << 3);
                b[f] = *reinterpret_cast<const bf16x8*>(&Bs[ib]);
            }
#pragma unroll
            for (int fm = 0; fm < 2; ++fm)
#pragma unroll
                for (int fn = 0; fn < 2; ++fn)
                    acc[fm][fn] = __builtin_amdgcn_mfma_f32_16x16x32_bf16(
                        a[fm], b[fn], acc[fm][fn], 0, 0, 0);
        }
    }

    if (LSM) {
        float* sm = reinterpret_cast<float*>(As);  // 64x64 f32 = 16KB <= As
        __syncthreads();
#pragma unroll
        for (int fm = 0; fm < 2; ++fm)
#pragma unroll
            for (int fn = 0; fn < 2; ++fn) {
                int c = wn * 32 + fn * 16 + (lane & 15);
                float bv = bias[colBase + c];
#pragma unroll
                for (int j = 0; j < 4; ++j) {
                    int r = wm * 32 + fm * 16 + 4 * (lane >> 4) + j;
                    sm[r * BN + c] = acc[fm][fn][j] + bv;
                }
            }
        __syncthreads();
        for (int rr = 0; rr < 16; ++rr) {
            int r = wid * 16 + rr;
            int gr = rowBase + r;
            if (gr >= M) continue;
            float v = sm[r * BN + lane];
            float m = v;
#pragma unroll
            for (int o = 32; o; o >>= 1) m = fmaxf(m, __shfl_xor(m, o));
            float ex = __expf(v - m);
            float s = ex;
#pragma unroll
            for (int o = 32; o; o >>= 1) s += __shfl_xor(s, o);
            ((float*)Cout)[(long)gr * N + lane] = v - m - __logf(s);
        }
    } else {
#pragma unroll
        for (int fm = 0; fm < 2; ++fm) {
#pragma unroll
            for (int fn = 0; fn < 2; ++fn) {
                int gc = colBase + wn * 32 + fn * 16 + (lane & 15);
                float bv = bias[gc];
#pragma unroll
                for (int j = 0; j < 4; ++j) {
                    int gr = rowBase + wm * 32 + fm * 16 + 4 * (lane >> 4) + j;
                    if (gr < M) {
                        float v = acc[fm][fn][j] + bv;
                        if (RELU) v = fmaxf(v, 0.0f);
                        if (OUT_BF16)
                            ((unsigned short*)Cout)[(long)gr * N + gc] =
                                f32_to_bf16_rne(v);
                        else
                            ((float*)Cout)[(long)gr * N + gc] = v;
                    }
                }
            }
        }
    }
}

// ---------------------------------------------------------------------------

extern "C" void kernel_launch(void* const* d_in, const int* in_sizes, int n_in,
                              void* d_out, int out_size, void* d_ws, size_t ws_size,
                              hipStream_t stream) {
    const float* x       = (const float*)d_in[0];
    const float* Wself1  = (const float*)d_in[1];
    const float* Wneigh1 = (const float*)d_in[2];
    const float* b1      = (const float*)d_in[3];
    const float* Wself2  = (const float*)d_in[4];
    const float* Wneigh2 = (const float*)d_in[5];
    const float* b2      = (const float*)d_in[6];
    const int* es1 = (const int*)d_in[7];
    const int* ed1 = (const int*)d_in[8];
    const int* es2 = (const int*)d_in[9];
    const int* ed2 = (const int*)d_in[10];
    const int E1 = in_sizes[7];
    const int E2 = in_sizes[9];
    const long NSRC = in_sizes[0] / D_IN;  // 100000

    // ---- workspace layout ----
    // ints: [cnt1 | cnt2] (memset) [csr1: SIZE1*SLOTS] [csr2: SIZE2*SLOTS]
    // bf16: [xb (mean2 overlays xb after gemm1)] [Wt1] [Wt2] [mean1] [h1]
    int* cnt1 = (int*)d_ws;                          // SIZE1
    int* cnt2 = cnt1 + SIZE1;                        // SIZE2
    int* csr1 = cnt2 + SIZE2;                        // SIZE1*SLOTS
    int* csr2 = csr1 + (size_t)SIZE1 * SLOTS;        // SIZE2*SLOTS
    size_t int_elems = (size_t)SIZE1 + SIZE2 +
                       (size_t)SIZE1 * SLOTS + (size_t)SIZE2 * SLOTS;
    int_elems = (int_elems + 3) & ~(size_t)3;        // 16B align
    unsigned short* xb    = (unsigned short*)((int*)d_ws + int_elems);  // NSRC*128
    unsigned short* mean2 = xb;  // overlay: xb dead before agg2 writes mean2
    unsigned short* Wt1   = xb + NSRC * D_IN;                 // 256*256
    unsigned short* Wt2   = Wt1 + (size_t)HID * (2 * D_IN);   // 64*512
    unsigned short* mean1 = Wt2 + (size_t)OUT_D * (2 * HID);  // SIZE1*128
    unsigned short* h1    = mean1 + (size_t)SIZE1 * D_IN;     // SIZE1*256

    hipMemsetAsync(d_ws, 0, (SIZE1 + SIZE2) * sizeof(int), stream);

    // ---- megafuse: sliced fills + conversions ----
    const long n4 = NSRC * D_IN / 4;                 // float4 groups in x
    const int f1 = ((E1 + ECH - 1) / ECH) * NXCD;    // 391*8
    const int f2 = f1 + ((E2 + ECH - 1) / ECH) * NXCD;
    const int f3 = f2 + (int)((n4 + 511) / 512);
    const int nb_cw = (HID * (2 * D_IN) + OUT_D * (2 * HID) + 255) / 256;
    megafuse<<<f3 + nb_cw, 256, 0, stream>>>(
        es1, ed1, E1, cnt1, csr1, es2, ed2, E2, cnt2, csr2,
        x, (unsigned*)xb, n4, Wself1, Wneigh1, Wself2, Wneigh2, Wt1, Wt2,
        f1, f2, f3);

    // ---- layer 1: pull-mean + GEMM(relu, bf16 out) ----
    agg_pull2<1><<<(SIZE1 + 3) / 4, 256, 0, stream>>>(
        (const uint4*)xb, csr1, cnt1, (uint4*)mean1, SIZE1);
    {
        dim3 grid((SIZE1 + 63) / 64, HID / 64);
        sage_gemm_mfma<D_IN, true, true, false><<<grid, 256, 0, stream>>>(
            xb, mean1, Wt1, b1, h1, SIZE1, HID);
    }

    // ---- layer 2: pull-mean + GEMM(+fused log_softmax, f32 out) ----
    agg_pull2<2><<<(SIZE2 + 3) / 4, 256, 0, stream>>>(
        (const uint4*)h1, csr2, cnt2, (uint4*)mean2, SIZE2);
    {
        dim3 grid((SIZE2 + 63) / 64, OUT_D / 64);
        sage_gemm_mfma<HID, false, false, true><<<grid, 256, 0, stream>>>(
            h1, mean2, Wt2, b2, d_out, SIZE2, OUT_D);
    }
}

// Round 8
// 152.966 us; speedup vs baseline: 1.0097x; 1.0097x over previous
//
#include <hip/hip_runtime.h>

// ---------------------------------------------------------------------------
// SAGE_DGL: 2-layer GraphSAGE (mean agg) forward on MI355X.
// Round 8 (on round-6 base; r7 slicing reverted):
//   - XCC-partitioned CSR slots: csr row = 8 segments x 16 slots (one 64B
//     line per XCD, picked by HW_REG_XCC_ID) + 48-slot shared overflow.
//     Writes to a line come from ONE XCD only -> L2 write merging without
//     blockIdx->XCD assumptions, edges read once. Capacity 16+48 >= max
//     degree, so results are exact even if XCC id were garbage (locality
//     hint only).
//   - fill2 fused into agg1 dispatch (independent; hides under gather).
//   - h1 overlays csr1 (dead after agg1); mean2 overlays xb.
// Pipeline: memset -> megafuse{fill1,convert_x,convert_w} -> agg1+fill2 ->
//           gemm1 -> agg2 -> gemm2+log_softmax.
// ---------------------------------------------------------------------------

constexpr int D_IN  = 128;
constexpr int HID   = 256;
constexpr int OUT_D = 64;
constexpr int SIZE1 = 25000;
constexpr int SIZE2 = 5000;
constexpr int SEGC  = 16;                 // slots per XCD segment (1 line)
constexpr int OVFS  = 48;                 // shared overflow slots
constexpr int ROW   = 8 * SEGC + OVFS;    // 176 ints per dst row
constexpr int ECH   = 2048;               // edges per fill block (256 x 8)

using bf16x8 = __attribute__((ext_vector_type(8))) short;
using f32x4  = __attribute__((ext_vector_type(4))) float;

__device__ inline unsigned short f32_to_bf16_rne(float f) {
    unsigned u = __builtin_bit_cast(unsigned, f);
    u = (u + 0x7fffu + ((u >> 16) & 1u)) >> 16;
    return (unsigned short)u;
}
__device__ inline float bf16_lo(unsigned u) {
    return __builtin_bit_cast(float, u << 16);
}
__device__ inline float bf16_hi(unsigned u) {
    return __builtin_bit_cast(float, u & 0xffff0000u);
}
__device__ inline unsigned pack_bf16(float lo, float hi) {
    return (unsigned)f32_to_bf16_rne(lo) | ((unsigned)f32_to_bf16_rne(hi) << 16);
}
__device__ inline void add8(float* a, uint4 v) {
    a[0] += bf16_lo(v.x); a[1] += bf16_hi(v.x);
    a[2] += bf16_lo(v.y); a[3] += bf16_hi(v.y);
    a[4] += bf16_lo(v.z); a[5] += bf16_hi(v.z);
    a[6] += bf16_lo(v.w); a[7] += bf16_hi(v.w);
}

// ---------------------------------------------------------------------------
// CSR fill body: one pass over an edge chunk; slot segment chosen by the
// wave's physical XCD id so each 64B csr line is written by one XCD only.
// ---------------------------------------------------------------------------
__device__ inline void fill_body(const int* __restrict__ es,
                                 const int* __restrict__ ed, int E, int base0,
                                 int* __restrict__ cnt, int* __restrict__ ovf,
                                 int* __restrict__ csr) {
    int xcc;
    asm volatile("s_getreg_b32 %0, hwreg(HW_REG_XCC_ID)" : "=s"(xcc));
    xcc &= 7;
#pragma unroll
    for (int j = 0; j < ECH / 256; ++j) {
        int e = base0 + j * 256;
        if (e < E) {
            int d = ed[e];
            int pos = atomicAdd(&cnt[d * 8 + xcc], 1);
            if (pos < SEGC) {
                csr[(long)d * ROW + xcc * SEGC + pos] = es[e];
            } else {
                int po = atomicAdd(&ovf[d], 1);
                if (po < OVFS) csr[(long)d * ROW + 8 * SEGC + po] = es[e];
            }
        }
    }
}

// ---------------------------------------------------------------------------
// Megafuse: [0,f1) fill1 | [f1,f2) convert x -> bf16 | [f2,..) convert W.
// ---------------------------------------------------------------------------
__global__ void megafuse(const int* __restrict__ es1, const int* __restrict__ ed1,
                         int E1, int* __restrict__ cnt1, int* __restrict__ ovf1,
                         int* __restrict__ csr1,
                         const float* __restrict__ x, unsigned* __restrict__ xb,
                         long n4,
                         const float* __restrict__ Ws1, const float* __restrict__ Wn1,
                         const float* __restrict__ Ws2, const float* __restrict__ Wn2,
                         unsigned short* __restrict__ Wt1,
                         unsigned short* __restrict__ Wt2,
                         int f1, int f2) {
    const int b = blockIdx.x;
    const int tid = threadIdx.x;
    if (b < f1) {                       // fill layer 1
        fill_body(es1, ed1, E1, b * ECH + tid, cnt1, ovf1, csr1);
    } else if (b < f2) {                // convert x -> bf16
        long i0 = (long)(b - f1) * 512 + tid;
#pragma unroll
        for (int j = 0; j < 2; ++j) {
            long i = i0 + j * 256;
            if (i < n4) {
                float4 v = reinterpret_cast<const float4*>(x)[i];
                uint2 o;
                o.x = pack_bf16(v.x, v.y);
                o.y = pack_bf16(v.z, v.w);
                reinterpret_cast<uint2*>(xb)[i] = o;
            }
        }
    } else {                            // convert weights
        int i = (b - f2) * 256 + tid;
        if (i < HID * (2 * D_IN)) {     // Wt1: 256 x 256
            int n = i >> 8, k = i & 255;
            float v = (k < D_IN) ? Ws1[k * HID + n] : Wn1[(k - D_IN) * HID + n];
            Wt1[i] = f32_to_bf16_rne(v);
        } else {
            int j = i - HID * (2 * D_IN);
            if (j < OUT_D * (2 * HID)) {  // Wt2: 64 x 512
                int n = j >> 9, k = j & 511;
                float v = (k < HID) ? Ws2[k * OUT_D + n] : Wn2[(k - HID) * OUT_D + n];
                Wt2[j] = f32_to_bf16_rne(v);
            }
        }
    }
}

// ---------------------------------------------------------------------------
// Pull-mean aggregation over segmented rows (bf16 in/out, fp32 acc).
// Wave per dst. Segment counts -> register prefix (all static indexing);
// logical edge j mapped to slot by unrolled compare/select chain.
// 4 groups x 16 lanes; 8-deep gather ILP; cross-group shfl reduce.
// FUSE: trailing blocks run fill_body for layer 2 (independent work).
// ---------------------------------------------------------------------------
template <int QPL, bool FUSE>
__global__ void agg_pull3(const uint4* __restrict__ X4,
                          const int* __restrict__ csr,
                          const int* __restrict__ cnt,
                          const int* __restrict__ ovf,
                          uint4* __restrict__ mean4, int ndst, int aggBlocks,
                          const int* __restrict__ esF, const int* __restrict__ edF,
                          int EF, int* __restrict__ cntF, int* __restrict__ ovfF,
                          int* __restrict__ csrF) {
    if (FUSE && (int)blockIdx.x >= aggBlocks) {
        fill_body(esF, edF, EF, ((int)blockIdx.x - aggBlocks) * ECH + threadIdx.x,
                  cntF, ovfF, csrF);
        return;
    }
    constexpr int R4 = QPL * 16;
    const int wid = threadIdx.x >> 6;
    const int lane = threadIdx.x & 63;
    const int d = blockIdx.x * 4 + wid;
    if (d >= ndst) return;

    int myc = 0;
    if (lane < 8) myc = min(cnt[d * 8 + lane], SEGC);
    else if (lane == 8) myc = min(ovf[d], OVFS);
    int cum[10];
    cum[0] = 0;
#pragma unroll
    for (int k = 0; k < 9; ++k) cum[k + 1] = cum[k] + __shfl(myc, k);
    const int n = cum[9];
    const long rowb = (long)d * ROW;

    const int g = lane >> 4;
    const int c = lane & 15;

    // j -> slot offset within row (static indexing only: rule #20)
    auto slot_of = [&](int j) {
        int slot = j;  // segment 0: 0*SEGC + (j - 0)
#pragma unroll
        for (int t = 1; t < 9; ++t)
            if (j >= cum[t]) slot = (t < 8 ? t * SEGC : 8 * SEGC) + (j - cum[t]);
        return slot;
    };

    float acc[QPL][8];
#pragma unroll
    for (int q = 0; q < QPL; ++q)
#pragma unroll
        for (int j = 0; j < 8; ++j) acc[q][j] = 0.0f;

    int j = g;
    for (; j + 28 < n; j += 32) {        // 8-deep main
        int s[8];
#pragma unroll
        for (int t = 0; t < 8; ++t) s[t] = csr[rowb + slot_of(j + 4 * t)];
#pragma unroll
        for (int q = 0; q < QPL; ++q) {
            uint4 v[8];
#pragma unroll
            for (int t = 0; t < 8; ++t) v[t] = X4[(long)s[t] * R4 + q * 16 + c];
#pragma unroll
            for (int t = 0; t < 8; ++t) add8(acc[q], v[t]);
        }
    }
    for (; j + 4 < n; j += 8) {          // 2-deep tail
        int s0 = csr[rowb + slot_of(j)];
        int s1 = csr[rowb + slot_of(j + 4)];
#pragma unroll
        for (int q = 0; q < QPL; ++q) {
            uint4 v0 = X4[(long)s0 * R4 + q * 16 + c];
            uint4 v1 = X4[(long)s1 * R4 + q * 16 + c];
            add8(acc[q], v0); add8(acc[q], v1);
        }
    }
    if (j < n) {                         // final edge
        long s0 = csr[rowb + slot_of(j)];
#pragma unroll
        for (int q = 0; q < QPL; ++q) {
            uint4 v0 = X4[s0 * R4 + q * 16 + c];
            add8(acc[q], v0);
        }
    }
#pragma unroll
    for (int q = 0; q < QPL; ++q)
#pragma unroll
        for (int jj = 0; jj < 8; ++jj) {
            acc[q][jj] += __shfl_xor(acc[q][jj], 16);
            acc[q][jj] += __shfl_xor(acc[q][jj], 32);
        }
    if (g == 0) {
        const float inv = 1.0f / (float)max(n, 1);
#pragma unroll
        for (int q = 0; q < QPL; ++q) {
            uint4 o;
            o.x = pack_bf16(acc[q][0] * inv, acc[q][1] * inv);
            o.y = pack_bf16(acc[q][2] * inv, acc[q][3] * inv);
            o.z = pack_bf16(acc[q][4] * inv, acc[q][5] * inv);
            o.w = pack_bf16(acc[q][6] * inv, acc[q][7] * inv);
            mean4[(long)d * R4 + q * 16 + c] = o;
        }
    }
}

// ---------------------------------------------------------------------------
// Fused SAGE GEMM via MFMA (bf16 in, fp32 acc).
// C[i][n] = act(Aself[i][:]@Wt[n][0:KPH] + Amean[i][:]@Wt[n][KPH:2KPH] + b[n])
// 64x64 tile, 4 waves (2x2), wave does 32x32 via 2x2 16x16x32 frags.
// LDS XOR-swizzled for conflict-free ds_read_b128.
// LSM=true: fuse row log_softmax (BN=64 == full row) via LDS tile + shfl.
// ---------------------------------------------------------------------------
template <int KPH, bool RELU, bool OUT_BF16, bool LSM>
__global__ __launch_bounds__(256) void sage_gemm_mfma(
    const unsigned short* __restrict__ Aself,
    const unsigned short* __restrict__ Amean,
    const unsigned short* __restrict__ Wt,
    const float* __restrict__ bias,
    void* __restrict__ Cout, int M, int N) {
    constexpr int BM = 64, BN = 64;
    constexpr int ITERS = (BM * KPH) / (256 * 8);
    __shared__ unsigned short As[BM * KPH];
    __shared__ unsigned short Bs[BN * KPH];

    const int tid = threadIdx.x;
    const int wid = tid >> 6;
    const int lane = tid & 63;
    const int wm = wid >> 1, wn = wid & 1;
    const int rowBase = blockIdx.x * BM;
    const int colBase = blockIdx.y * BN;

    f32x4 acc[2][2];
#pragma unroll
    for (int a = 0; a < 2; ++a)
#pragma unroll
        for (int b = 0; b < 2; ++b)
#pragma unroll
            for (int j = 0; j < 4; ++j) acc[a][b][j] = 0.0f;

#pragma unroll
    for (int p = 0; p < 2; ++p) {
        const unsigned short* __restrict__ A = p ? Amean : Aself;
        __syncthreads();
#pragma unroll
        for (int it = 0; it < ITERS; ++it) {
            int flat = (it * 256 + tid) * 8;
            int r = flat / KPH, kc = flat % KPH;
            int gr = rowBase + r;
            if (gr >= M) gr = M - 1;
            uint4 v = *reinterpret_cast<const uint4*>(&A[(long)gr * KPH + kc]);
            int idx = (r * KPH + kc) ^ ((r & 7) << 3);
            *reinterpret_cast<uint4*>(&As[idx]) = v;
        }
#pragma unroll
        for (int it = 0; it < ITERS; ++it) {
            int flat = (it * 256 + tid) * 8;
            int r = flat / KPH, kc = flat % KPH;
            uint4 v = *reinterpret_cast<const uint4*>(
                &Wt[(long)(colBase + r) * (2 * KPH) + p * KPH + kc]);
            int idx = (r * KPH + kc) ^ ((r & 7) << 3);
            *reinterpret_cast<uint4*>(&Bs[idx]) = v;
        }
        __syncthreads();
#pragma unroll
        for (int kk = 0; kk < KPH / 32; ++kk) {
            bf16x8 a[2], b[2];
            const int kb = kk * 32 + 8 * (lane >> 4);
#pragma unroll
            for (int f = 0; f < 2; ++f) {
                int r = wm * 32 + f * 16 + (lane & 15);
                int ia = (r * KPH + kb) ^ ((r & 7) << 3);
                a[f] = *reinterpret_cast<const bf16x8*>(&As[ia]);
                int rn = wn * 32 + f * 16 + (lane & 15);
                int ib = (rn * KPH + kb) ^ ((rn & 7) << 3);
                b[f] = *reinterpret_cast<const bf16x8*>(&Bs[ib]);
            }
#pragma unroll
            for (int fm = 0; fm < 2; ++fm)
#pragma unroll
                for (int fn = 0; fn < 2; ++fn)
                    acc[fm][fn] = __builtin_amdgcn_mfma_f32_16x16x32_bf16(
                        a[fm], b[fn], acc[fm][fn], 0, 0, 0);
        }
    }

    if (LSM) {
        float* sm = reinterpret_cast<float*>(As);  // 64x64 f32 = 16KB <= As
        __syncthreads();
#pragma unroll
        for (int fm = 0; fm < 2; ++fm)
#pragma unroll
            for (int fn = 0; fn < 2; ++fn) {
                int c = wn * 32 + fn * 16 + (lane & 15);
                float bv = bias[colBase + c];
#pragma unroll
                for (int j = 0; j < 4; ++j) {
                    int r = wm * 32 + fm * 16 + 4 * (lane >> 4) + j;
                    sm[r * BN + c] = acc[fm][fn][j] + bv;
                }
            }
        __syncthreads();
        for (int rr = 0; rr < 16; ++rr) {
            int r = wid * 16 + rr;
            int gr = rowBase + r;
            if (gr >= M) continue;
            float v = sm[r * BN + lane];
            float m = v;
#pragma unroll
            for (int o = 32; o; o >>= 1) m = fmaxf(m, __shfl_xor(m, o));
            float ex = __expf(v - m);
            float s = ex;
#pragma unroll
            for (int o = 32; o; o >>= 1) s += __shfl_xor(s, o);
            ((float*)Cout)[(long)gr * N + lane] = v - m - __logf(s);
        }
    } else {
#pragma unroll
        for (int fm = 0; fm < 2; ++fm) {
#pragma unroll
            for (int fn = 0; fn < 2; ++fn) {
                int gc = colBase + wn * 32 + fn * 16 + (lane & 15);
                float bv = bias[gc];
#pragma unroll
                for (int j = 0; j < 4; ++j) {
                    int gr = rowBase + wm * 32 + fm * 16 + 4 * (lane >> 4) + j;
                    if (gr < M) {
                        float v = acc[fm][fn][j] + bv;
                        if (RELU) v = fmaxf(v, 0.0f);
                        if (OUT_BF16)
                            ((unsigned short*)Cout)[(long)gr * N + gc] =
                                f32_to_bf16_rne(v);
                        else
                            ((float*)Cout)[(long)gr * N + gc] = v;
                    }
                }
            }
        }
    }
}

// ---------------------------------------------------------------------------

extern "C" void kernel_launch(void* const* d_in, const int* in_sizes, int n_in,
                              void* d_out, int out_size, void* d_ws, size_t ws_size,
                              hipStream_t stream) {
    const float* x       = (const float*)d_in[0];
    const float* Wself1  = (const float*)d_in[1];
    const float* Wneigh1 = (const float*)d_in[2];
    const float* b1      = (const float*)d_in[3];
    const float* Wself2  = (const float*)d_in[4];
    const float* Wneigh2 = (const float*)d_in[5];
    const float* b2      = (const float*)d_in[6];
    const int* es1 = (const int*)d_in[7];
    const int* ed1 = (const int*)d_in[8];
    const int* es2 = (const int*)d_in[9];
    const int* ed2 = (const int*)d_in[10];
    const int E1 = in_sizes[7];
    const int E2 = in_sizes[9];
    const long NSRC = in_sizes[0] / D_IN;  // 100000

    // ---- workspace layout ----
    // ints: [cnt1:S1*8][ovf1:S1][cnt2:S2*8][ovf2:S2] (memset 270000 ints)
    //       [csr2: S2*ROW][csr1: S1*ROW]   (h1 overlays csr1 after agg1)
    // bf16: [xb (mean2 overlay)][Wt1][Wt2][mean1]
    int* cnt1 = (int*)d_ws;                          // SIZE1*8
    int* ovf1 = cnt1 + (size_t)SIZE1 * 8;            // SIZE1
    int* cnt2 = ovf1 + SIZE1;                        // SIZE2*8
    int* ovf2 = cnt2 + (size_t)SIZE2 * 8;            // SIZE2
    int* csr2 = ovf2 + SIZE2;                        // SIZE2*ROW
    int* csr1 = csr2 + (size_t)SIZE2 * ROW;          // SIZE1*ROW
    const size_t zero_ints = (size_t)SIZE1 * 9 + (size_t)SIZE2 * 9;  // 270000
    const size_t int_elems = zero_ints + (size_t)SIZE2 * ROW + (size_t)SIZE1 * ROW;
    unsigned short* xb    = (unsigned short*)((int*)d_ws + int_elems);  // NSRC*128
    unsigned short* mean2 = xb;                      // overlay (xb dead by agg2)
    unsigned short* Wt1   = xb + NSRC * D_IN;        // 256*256
    unsigned short* Wt2   = Wt1 + (size_t)HID * (2 * D_IN);   // 64*512
    unsigned short* mean1 = Wt2 + (size_t)OUT_D * (2 * HID);  // SIZE1*128
    unsigned short* h1    = (unsigned short*)csr1;   // overlay (csr1 dead by gemm1)

    hipMemsetAsync(d_ws, 0, zero_ints * sizeof(int), stream);

    // ---- megafuse: fill1 + conversions ----
    const long n4 = NSRC * D_IN / 4;                 // float4 groups in x
    const int f1 = (E1 + ECH - 1) / ECH;             // 391
    const int f2 = f1 + (int)((n4 + 511) / 512);
    const int nb_cw = (HID * (2 * D_IN) + OUT_D * (2 * HID) + 255) / 256;
    megafuse<<<f2 + nb_cw, 256, 0, stream>>>(
        es1, ed1, E1, cnt1, ovf1, csr1,
        x, (unsigned*)xb, n4, Wself1, Wneigh1, Wself2, Wneigh2, Wt1, Wt2,
        f1, f2);

    // ---- layer 1: pull-mean (+ fused fill2) + GEMM(relu, bf16 out) ----
    {
        const int aggB = (SIZE1 + 3) / 4;            // 6250
        const int fillB = (E2 + ECH - 1) / ECH;      // 79
        agg_pull3<1, true><<<aggB + fillB, 256, 0, stream>>>(
            (const uint4*)xb, csr1, cnt1, ovf1, (uint4*)mean1, SIZE1, aggB,
            es2, ed2, E2, cnt2, ovf2, csr2);
    }
    {
        dim3 grid((SIZE1 + 63) / 64, HID / 64);
        sage_gemm_mfma<D_IN, true, true, false><<<grid, 256, 0, stream>>>(
            xb, mean1, Wt1, b1, h1, SIZE1, HID);
    }

    // ---- layer 2: pull-mean + GEMM(+fused log_softmax, f32 out) ----
    agg_pull3<2, false><<<(SIZE2 + 3) / 4, 256, 0, stream>>>(
        (const uint4*)h1, csr2, cnt2, ovf2, (uint4*)mean2, SIZE2, 1 << 30,
        nullptr, nullptr, 0, nullptr, nullptr, nullptr);
    {
        dim3 grid((SIZE2 + 63) / 64, OUT_D / 64);
        sage_gemm_mfma<HID, false, false, true><<<grid, 256, 0, stream>>>(
            h1, mean2, Wt2, b2, d_out, SIZE2, OUT_D);
    }
}

// Round 10
// 152.202 us; speedup vs baseline: 1.0148x; 1.0050x over previous
//
#include <hip/hip_runtime.h>

// ---------------------------------------------------------------------------
// SAGE_DGL: 2-layer GraphSAGE (mean agg) forward on MI355X.
// Round 10 (fixes round 9's EXEC-mask shfl hazard):
//   - agg: lane-register edge indices; ALL __shfl (ds_bpermute) executed at
//     full wave activity (uniform trip counts; predication only after the
//     shfl). Round 9 diverged lane-groups around the shfl -> inactive source
//     lanes -> garbage indices (ds_bpermute honors EXEC).
//   - XCC-partitioned CSR fill (r8), fill2 fused in agg1, overlays kept.
// Pipeline: memset -> megafuse{fill1,convert_x,convert_w} -> agg1+fill2 ->
//           gemm1 -> agg2 -> gemm2+log_softmax.
// ---------------------------------------------------------------------------

constexpr int D_IN  = 128;
constexpr int HID   = 256;
constexpr int OUT_D = 64;
constexpr int SIZE1 = 25000;
constexpr int SIZE2 = 5000;
constexpr int SEGC  = 16;                 // slots per XCD segment (1 line)
constexpr int OVFS  = 48;                 // shared overflow slots
constexpr int ROW   = 8 * SEGC + OVFS;    // 176 ints per dst row
constexpr int ECH   = 2048;               // edges per fill block (256 x 8)

using bf16x8 = __attribute__((ext_vector_type(8))) short;
using f32x4  = __attribute__((ext_vector_type(4))) float;

__device__ inline unsigned short f32_to_bf16_rne(float f) {
    unsigned u = __builtin_bit_cast(unsigned, f);
    u = (u + 0x7fffu + ((u >> 16) & 1u)) >> 16;
    return (unsigned short)u;
}
__device__ inline float bf16_lo(unsigned u) {
    return __builtin_bit_cast(float, u << 16);
}
__device__ inline float bf16_hi(unsigned u) {
    return __builtin_bit_cast(float, u & 0xffff0000u);
}
__device__ inline unsigned pack_bf16(float lo, float hi) {
    return (unsigned)f32_to_bf16_rne(lo) | ((unsigned)f32_to_bf16_rne(hi) << 16);
}
__device__ inline void add8(float* a, uint4 v) {
    a[0] += bf16_lo(v.x); a[1] += bf16_hi(v.x);
    a[2] += bf16_lo(v.y); a[3] += bf16_hi(v.y);
    a[4] += bf16_lo(v.z); a[5] += bf16_hi(v.z);
    a[6] += bf16_lo(v.w); a[7] += bf16_hi(v.w);
}

// ---------------------------------------------------------------------------
// CSR fill body: slot segment chosen by the wave's physical XCD id so each
// 64B csr line is written by one XCD only (L2 write merging).
// ---------------------------------------------------------------------------
__device__ inline void fill_body(const int* __restrict__ es,
                                 const int* __restrict__ ed, int E, int base0,
                                 int* __restrict__ cnt, int* __restrict__ ovf,
                                 int* __restrict__ csr) {
    int xcc;
    asm volatile("s_getreg_b32 %0, hwreg(HW_REG_XCC_ID)" : "=s"(xcc));
    xcc &= 7;
#pragma unroll
    for (int j = 0; j < ECH / 256; ++j) {
        int e = base0 + j * 256;
        if (e < E) {
            int d = ed[e];
            int pos = atomicAdd(&cnt[d * 8 + xcc], 1);
            if (pos < SEGC) {
                csr[(long)d * ROW + xcc * SEGC + pos] = es[e];
            } else {
                int po = atomicAdd(&ovf[d], 1);
                if (po < OVFS) csr[(long)d * ROW + 8 * SEGC + po] = es[e];
            }
        }
    }
}

// ---------------------------------------------------------------------------
// Megafuse: [0,f1) fill1 | [f1,f2) convert x -> bf16 | [f2,..) convert W.
// ---------------------------------------------------------------------------
__global__ void megafuse(const int* __restrict__ es1, const int* __restrict__ ed1,
                         int E1, int* __restrict__ cnt1, int* __restrict__ ovf1,
                         int* __restrict__ csr1,
                         const float* __restrict__ x, unsigned* __restrict__ xb,
                         long n4,
                         const float* __restrict__ Ws1, const float* __restrict__ Wn1,
                         const float* __restrict__ Ws2, const float* __restrict__ Wn2,
                         unsigned short* __restrict__ Wt1,
                         unsigned short* __restrict__ Wt2,
                         int f1, int f2) {
    const int b = blockIdx.x;
    const int tid = threadIdx.x;
    if (b < f1) {                       // fill layer 1
        fill_body(es1, ed1, E1, b * ECH + tid, cnt1, ovf1, csr1);
    } else if (b < f2) {                // convert x -> bf16
        long i0 = (long)(b - f1) * 512 + tid;
#pragma unroll
        for (int j = 0; j < 2; ++j) {
            long i = i0 + j * 256;
            if (i < n4) {
                float4 v = reinterpret_cast<const float4*>(x)[i];
                uint2 o;
                o.x = pack_bf16(v.x, v.y);
                o.y = pack_bf16(v.z, v.w);
                reinterpret_cast<uint2*>(xb)[i] = o;
            }
        }
    } else {                            // convert weights
        int i = (b - f2) * 256 + tid;
        if (i < HID * (2 * D_IN)) {     // Wt1: 256 x 256
            int n = i >> 8, k = i & 255;
            float v = (k < D_IN) ? Ws1[k * HID + n] : Wn1[(k - D_IN) * HID + n];
            Wt1[i] = f32_to_bf16_rne(v);
        } else {
            int j = i - HID * (2 * D_IN);
            if (j < OUT_D * (2 * HID)) {  // Wt2: 64 x 512
                int n = j >> 9, k = j & 511;
                float v = (k < HID) ? Ws2[k * OUT_D + n] : Wn2[(k - HID) * OUT_D + n];
                Wt2[j] = f32_to_bf16_rne(v);
            }
        }
    }
}

// ---------------------------------------------------------------------------
// Pull-mean aggregation, lane-register indices, EXEC-safe shfl schedule.
// Wave per dst. Lane j resolves edge j's slot once and loads its src index.
// Gather: nI8 full 32-edge rounds (uniform trip count -> all shfls at full
// wave activity), then one predicated remainder round (shfls unconditional,
// loads/adds guarded per lane-group). Exact direct-read tail for n > 64.
// 4 groups x 16 lanes; 8-deep gather ILP; cross-group shfl reduce.
// FUSE: trailing blocks run fill_body for layer 2.
// ---------------------------------------------------------------------------
template <int QPL, bool FUSE>
__global__ void agg_pull5(const uint4* __restrict__ X4,
                          const int* __restrict__ csr,
                          const int* __restrict__ cnt,
                          const int* __restrict__ ovf,
                          uint4* __restrict__ mean4, int ndst, int aggBlocks,
                          const int* __restrict__ esF, const int* __restrict__ edF,
                          int EF, int* __restrict__ cntF, int* __restrict__ ovfF,
                          int* __restrict__ csrF) {
    if (FUSE && (int)blockIdx.x >= aggBlocks) {
        fill_body(esF, edF, EF, ((int)blockIdx.x - aggBlocks) * ECH + threadIdx.x,
                  cntF, ovfF, csrF);
        return;
    }
    constexpr int R4 = QPL * 16;
    const int wid = threadIdx.x >> 6;
    const int lane = threadIdx.x & 63;
    const int d = blockIdx.x * 4 + wid;
    if (d >= ndst) return;   // wave-uniform (ndst divisible by 4); no barriers

    int myc = 0;
    if (lane < 8) myc = min(cnt[d * 8 + lane], SEGC);
    else if (lane == 8) myc = min(ovf[d], OVFS);
    int cum[10];
    cum[0] = 0;
#pragma unroll
    for (int k = 0; k < 9; ++k) cum[k + 1] = cum[k] + __shfl(myc, k);
    const int n = cum[9];
    const long rowb = (long)d * ROW;

    // lane = edge index: resolve slot once, fetch src idx into register
    int slot = lane;
#pragma unroll
    for (int t = 1; t < 9; ++t)
        if (lane >= cum[t]) slot = (t < 8 ? t * SEGC : 8 * SEGC) + (lane - cum[t]);
    int myidx = 0;
    if (lane < n) myidx = csr[rowb + slot];

    const int g = lane >> 4;
    const int c = lane & 15;
    const int nmain = min(n, 64);

    float acc[QPL][8];
#pragma unroll
    for (int q = 0; q < QPL; ++q)
#pragma unroll
        for (int j = 0; j < 8; ++j) acc[q][j] = 0.0f;

    // full 32-edge rounds: trip count uniform -> every shfl at full activity
    const int nI8 = nmain >> 5;
    for (int i = 0; i < nI8; ++i) {
        const int e0 = i * 32 + g;
        int s[8];
#pragma unroll
        for (int t = 0; t < 8; ++t) s[t] = __shfl(myidx, e0 + 4 * t);
#pragma unroll
        for (int q = 0; q < QPL; ++q) {
            uint4 v[8];
#pragma unroll
            for (int t = 0; t < 8; ++t) v[t] = X4[(long)s[t] * R4 + q * 16 + c];
#pragma unroll
            for (int t = 0; t < 8; ++t) add8(acc[q], v[t]);
        }
    }
    // remainder (< 32 edges): shfls unconditional, loads/adds predicated
    if (nI8 * 32 < nmain) {
        const int e0 = nI8 * 32 + g;
        int s[8];
#pragma unroll
        for (int t = 0; t < 8; ++t) s[t] = __shfl(myidx, (e0 + 4 * t) & 63);
#pragma unroll
        for (int t = 0; t < 8; ++t) {
            if (e0 + 4 * t < nmain) {
#pragma unroll
                for (int q = 0; q < QPL; ++q) {
                    uint4 v = X4[(long)s[t] * R4 + q * 16 + c];
                    add8(acc[q], v);
                }
            }
        }
    }
    // exact rare tail for n > 64: direct csr reads with per-edge slot chain
    for (int j2 = 64 + g; j2 < n; j2 += 4) {
        int sl = j2;
#pragma unroll
        for (int t = 1; t < 9; ++t)
            if (j2 >= cum[t]) sl = (t < 8 ? t * SEGC : 8 * SEGC) + (j2 - cum[t]);
        long s0 = csr[rowb + sl];
#pragma unroll
        for (int q = 0; q < QPL; ++q) {
            uint4 v0 = X4[s0 * R4 + q * 16 + c];
            add8(acc[q], v0);
        }
    }
#pragma unroll
    for (int q = 0; q < QPL; ++q)
#pragma unroll
        for (int jj = 0; jj < 8; ++jj) {
            acc[q][jj] += __shfl_xor(acc[q][jj], 16);
            acc[q][jj] += __shfl_xor(acc[q][jj], 32);
        }
    if (g == 0) {
        const float inv = 1.0f / (float)max(n, 1);
#pragma unroll
        for (int q = 0; q < QPL; ++q) {
            uint4 o;
            o.x = pack_bf16(acc[q][0] * inv, acc[q][1] * inv);
            o.y = pack_bf16(acc[q][2] * inv, acc[q][3] * inv);
            o.z = pack_bf16(acc[q][4] * inv, acc[q][5] * inv);
            o.w = pack_bf16(acc[q][6] * inv, acc[q][7] * inv);
            mean4[(long)d * R4 + q * 16 + c] = o;
        }
    }
}

// ---------------------------------------------------------------------------
// Fused SAGE GEMM via MFMA (bf16 in, fp32 acc).
// C[i][n] = act(Aself[i][:]@Wt[n][0:KPH] + Amean[i][:]@Wt[n][KPH:2KPH] + b[n])
// 64x64 tile, 4 waves (2x2), wave does 32x32 via 2x2 16x16x32 frags.
// LDS XOR-swizzled for conflict-free ds_read_b128.
// LSM=true: fuse row log_softmax (BN=64 == full row) via LDS tile + shfl.
// ---------------------------------------------------------------------------
template <int KPH, bool RELU, bool OUT_BF16, bool LSM>
__global__ __launch_bounds__(256) void sage_gemm_mfma(
    const unsigned short* __restrict__ Aself,
    const unsigned short* __restrict__ Amean,
    const unsigned short* __restrict__ Wt,
    const float* __restrict__ bias,
    void* __restrict__ Cout, int M, int N) {
    constexpr int BM = 64, BN = 64;
    constexpr int ITERS = (BM * KPH) / (256 * 8);
    __shared__ unsigned short As[BM * KPH];
    __shared__ unsigned short Bs[BN * KPH];

    const int tid = threadIdx.x;
    const int wid = tid >> 6;
    const int lane = tid & 63;
    const int wm = wid >> 1, wn = wid & 1;
    const int rowBase = blockIdx.x * BM;
    const int colBase = blockIdx.y * BN;

    f32x4 acc[2][2];
#pragma unroll
    for (int a = 0; a < 2; ++a)
#pragma unroll
        for (int b = 0; b < 2; ++b)
#pragma unroll
            for (int j = 0; j < 4; ++j) acc[a][b][j] = 0.0f;

#pragma unroll
    for (int p = 0; p < 2; ++p) {
        const unsigned short* __restrict__ A = p ? Amean : Aself;
        __syncthreads();
#pragma unroll
        for (int it = 0; it < ITERS; ++it) {
            int flat = (it * 256 + tid) * 8;
            int r = flat / KPH, kc = flat % KPH;
            int gr = rowBase + r;
            if (gr >= M) gr = M - 1;
            uint4 v = *reinterpret_cast<const uint4*>(&A[(long)gr * KPH + kc]);
            int idx = (r * KPH + kc) ^ ((r & 7) << 3);
            *reinterpret_cast<uint4*>(&As[idx]) = v;
        }
#pragma unroll
        for (int it = 0; it < ITERS; ++it) {
            int flat = (it * 256 + tid) * 8;
            int r = flat / KPH, kc = flat % KPH;
            uint4 v = *reinterpret_cast<const uint4*>(
                &Wt[(long)(colBase + r) * (2 * KPH) + p * KPH + kc]);
            int idx = (r * KPH + kc) ^ ((r & 7) << 3);
            *reinterpret_cast<uint4*>(&Bs[idx]) = v;
        }
        __syncthreads();
#pragma unroll
        for (int kk = 0; kk < KPH / 32; ++kk) {
            bf16x8 a[2], b[2];
            const int kb = kk * 32 + 8 * (lane >> 4);
#pragma unroll
            for (int f = 0; f < 2; ++f) {
                int r = wm * 32 + f * 16 + (lane & 15);
                int ia = (r * KPH + kb) ^ ((r & 7) << 3);
                a[f] = *reinterpret_cast<const bf16x8*>(&As[ia]);
                int rn = wn * 32 + f * 16 + (lane & 15);
                int ib = (rn * KPH + kb) ^ ((rn & 7) << 3);
                b[f] = *reinterpret_cast<const bf16x8*>(&Bs[ib]);
            }
#pragma unroll
            for (int fm = 0; fm < 2; ++fm)
#pragma unroll
                for (int fn = 0; fn < 2; ++fn)
                    acc[fm][fn] = __builtin_amdgcn_mfma_f32_16x16x32_bf16(
                        a[fm], b[fn], acc[fm][fn], 0, 0, 0);
        }
    }

    if (LSM) {
        float* sm = reinterpret_cast<float*>(As);  // 64x64 f32 = 16KB <= As
        __syncthreads();
#pragma unroll
        for (int fm = 0; fm < 2; ++fm)
#pragma unroll
            for (int fn = 0; fn < 2; ++fn) {
                int c = wn * 32 + fn * 16 + (lane & 15);
                float bv = bias[colBase + c];
#pragma unroll
                for (int j = 0; j < 4; ++j) {
                    int r = wm * 32 + fm * 16 + 4 * (lane >> 4) + j;
                    sm[r * BN + c] = acc[fm][fn][j] + bv;
                }
            }
        __syncthreads();
        for (int rr = 0; rr < 16; ++rr) {
            int r = wid * 16 + rr;
            int gr = rowBase + r;
            if (gr >= M) continue;
            float v = sm[r * BN + lane];
            float m = v;
#pragma unroll
            for (int o = 32; o; o >>= 1) m = fmaxf(m, __shfl_xor(m, o));
            float ex = __expf(v - m);
            float s = ex;
#pragma unroll
            for (int o = 32; o; o >>= 1) s += __shfl_xor(s, o);
            ((float*)Cout)[(long)gr * N + lane] = v - m - __logf(s);
        }
    } else {
#pragma unroll
        for (int fm = 0; fm < 2; ++fm) {
#pragma unroll
            for (int fn = 0; fn < 2; ++fn) {
                int gc = colBase + wn * 32 + fn * 16 + (lane & 15);
                float bv = bias[gc];
#pragma unroll
                for (int j = 0; j < 4; ++j) {
                    int gr = rowBase + wm * 32 + fm * 16 + 4 * (lane >> 4) + j;
                    if (gr < M) {
                        float v = acc[fm][fn][j] + bv;
                        if (RELU) v = fmaxf(v, 0.0f);
                        if (OUT_BF16)
                            ((unsigned short*)Cout)[(long)gr * N + gc] =
                                f32_to_bf16_rne(v);
                        else
                            ((float*)Cout)[(long)gr * N + gc] = v;
                    }
                }
            }
        }
    }
}

// ---------------------------------------------------------------------------

extern "C" void kernel_launch(void* const* d_in, const int* in_sizes, int n_in,
                              void* d_out, int out_size, void* d_ws, size_t ws_size,
                              hipStream_t stream) {
    const float* x       = (const float*)d_in[0];
    const float* Wself1  = (const float*)d_in[1];
    const float* Wneigh1 = (const float*)d_in[2];
    const float* b1      = (const float*)d_in[3];
    const float* Wself2  = (const float*)d_in[4];
    const float* Wneigh2 = (const float*)d_in[5];
    const float* b2      = (const float*)d_in[6];
    const int* es1 = (const int*)d_in[7];
    const int* ed1 = (const int*)d_in[8];
    const int* es2 = (const int*)d_in[9];
    const int* ed2 = (const int*)d_in[10];
    const int E1 = in_sizes[7];
    const int E2 = in_sizes[9];
    const long NSRC = in_sizes[0] / D_IN;  // 100000

    // ---- workspace layout ----
    // ints: [cnt1:S1*8][ovf1:S1][cnt2:S2*8][ovf2:S2] (memset 270000 ints)
    //       [csr2: S2*ROW][csr1: S1*ROW]   (h1 overlays csr1 after agg1)
    // bf16: [xb (mean2 overlay)][Wt1][Wt2][mean1]
    int* cnt1 = (int*)d_ws;                          // SIZE1*8
    int* ovf1 = cnt1 + (size_t)SIZE1 * 8;            // SIZE1
    int* cnt2 = ovf1 + SIZE1;                        // SIZE2*8
    int* ovf2 = cnt2 + (size_t)SIZE2 * 8;            // SIZE2
    int* csr2 = ovf2 + SIZE2;                        // SIZE2*ROW
    int* csr1 = csr2 + (size_t)SIZE2 * ROW;          // SIZE1*ROW
    const size_t zero_ints = (size_t)SIZE1 * 9 + (size_t)SIZE2 * 9;  // 270000
    const size_t int_elems = zero_ints + (size_t)SIZE2 * ROW + (size_t)SIZE1 * ROW;
    unsigned short* xb    = (unsigned short*)((int*)d_ws + int_elems);  // NSRC*128
    unsigned short* mean2 = xb;                      // overlay (xb dead by agg2)
    unsigned short* Wt1   = xb + NSRC * D_IN;        // 256*256
    unsigned short* Wt2   = Wt1 + (size_t)HID * (2 * D_IN);   // 64*512
    unsigned short* mean1 = Wt2 + (size_t)OUT_D * (2 * HID);  // SIZE1*128
    unsigned short* h1    = (unsigned short*)csr1;   // overlay (csr1 dead by gemm1)

    hipMemsetAsync(d_ws, 0, zero_ints * sizeof(int), stream);

    // ---- megafuse: fill1 + conversions ----
    const long n4 = NSRC * D_IN / 4;                 // float4 groups in x
    const int f1 = (E1 + ECH - 1) / ECH;             // 391
    const int f2 = f1 + (int)((n4 + 511) / 512);
    const int nb_cw = (HID * (2 * D_IN) + OUT_D * (2 * HID) + 255) / 256;
    megafuse<<<f2 + nb_cw, 256, 0, stream>>>(
        es1, ed1, E1, cnt1, ovf1, csr1,
        x, (unsigned*)xb, n4, Wself1, Wneigh1, Wself2, Wneigh2, Wt1, Wt2,
        f1, f2);

    // ---- layer 1: pull-mean (+ fused fill2) + GEMM(relu, bf16 out) ----
    {
        const int aggB = (SIZE1 + 3) / 4;            // 6250
        const int fillB = (E2 + ECH - 1) / ECH;      // 79
        agg_pull5<1, true><<<aggB + fillB, 256, 0, stream>>>(
            (const uint4*)xb, csr1, cnt1, ovf1, (uint4*)mean1, SIZE1, aggB,
            es2, ed2, E2, cnt2, ovf2, csr2);
    }
    {
        dim3 grid((SIZE1 + 63) / 64, HID / 64);
        sage_gemm_mfma<D_IN, true, true, false><<<grid, 256, 0, stream>>>(
            xb, mean1, Wt1, b1, h1, SIZE1, HID);
    }

    // ---- layer 2: pull-mean + GEMM(+fused log_softmax, f32 out) ----
    agg_pull5<2, false><<<(SIZE2 + 3) / 4, 256, 0, stream>>>(
        (const uint4*)h1, csr2, cnt2, ovf2, (uint4*)mean2, SIZE2, 1 << 30,
        nullptr, nullptr, 0, nullptr, nullptr, nullptr);
    {
        dim3 grid((SIZE2 + 63) / 64, OUT_D / 64);
        sage_gemm_mfma<HID, false, false, true><<<grid, 256, 0, stream>>>(
            h1, mean2, Wt2, b2, d_out, SIZE2, OUT_D);
    }
}

// Round 11
// 129.904 us; speedup vs baseline: 1.1890x; 1.1717x over previous
//
#include <hip/hip_runtime.h>

// ---------------------------------------------------------------------------
// SAGE_DGL: 2-layer GraphSAGE (mean agg) forward on MI355X.
// Round 11 (on round-10 base):
//   - fp8(e4m3) for the GATHERED data only: x8 (all 100k rows) and h8
//     (fp8 copy of h1 written in gemm1 epilogue). Neighbor-mean paths read
//     fp8 (half the 64B lines per edge, 2x edges in flight); both GEMM
//     self-paths and all GEMM inputs stay bf16. Mean noise ~ fp8err/sqrt(32).
//   - agg geometry: GL lanes/group (GL=8 for 128B rows, 16 for 256B rows),
//     EXEC-safe shfl schedule (uniform rounds, predication after shfl).
//   - xb shrinks to 25k rows (GEMM1 self input only).
// Pipeline: memset -> megafuse{fill1,convert,convert_w} -> agg1(fp8)+fill2 ->
//           gemm1(+h8 epilogue) -> agg2(fp8) -> gemm2+log_softmax.
// ---------------------------------------------------------------------------

constexpr int D_IN  = 128;
constexpr int HID   = 256;
constexpr int OUT_D = 64;
constexpr int SIZE1 = 25000;
constexpr int SIZE2 = 5000;
constexpr int SEGC  = 16;                 // slots per XCD segment (1 line)
constexpr int OVFS  = 48;                 // shared overflow slots
constexpr int ROW   = 8 * SEGC + OVFS;    // 176 ints per dst row
constexpr int ECH   = 2048;               // edges per fill block (256 x 8)

using bf16x8 = __attribute__((ext_vector_type(8))) short;
using f32x4  = __attribute__((ext_vector_type(4))) float;
using f32x2  = __attribute__((ext_vector_type(2))) float;

__device__ inline unsigned short f32_to_bf16_rne(float f) {
    unsigned u = __builtin_bit_cast(unsigned, f);
    u = (u + 0x7fffu + ((u >> 16) & 1u)) >> 16;
    return (unsigned short)u;
}
__device__ inline unsigned pack_bf16(float lo, float hi) {
    return (unsigned)f32_to_bf16_rne(lo) | ((unsigned)f32_to_bf16_rne(hi) << 16);
}
// accumulate 16 fp8 values (one uint4) into a[0..15]
__device__ inline void add16(float* a, uint4 v) {
    const unsigned u[4] = {v.x, v.y, v.z, v.w};
#pragma unroll
    for (int i = 0; i < 4; ++i) {
        f32x2 f0 = __builtin_amdgcn_cvt_pk_f32_fp8(u[i], false);  // bytes 0,1
        f32x2 f1 = __builtin_amdgcn_cvt_pk_f32_fp8(u[i], true);   // bytes 2,3
        a[i * 4 + 0] += f0.x; a[i * 4 + 1] += f0.y;
        a[i * 4 + 2] += f1.x; a[i * 4 + 3] += f1.y;
    }
}

// ---------------------------------------------------------------------------
// CSR fill body: slot segment chosen by the wave's physical XCD id so each
// 64B csr line is written by one XCD only (L2 write merging).
// ---------------------------------------------------------------------------
__device__ inline void fill_body(const int* __restrict__ es,
                                 const int* __restrict__ ed, int E, int base0,
                                 int* __restrict__ cnt, int* __restrict__ ovf,
                                 int* __restrict__ csr) {
    int xcc;
    asm volatile("s_getreg_b32 %0, hwreg(HW_REG_XCC_ID)" : "=s"(xcc));
    xcc &= 7;
#pragma unroll
    for (int j = 0; j < ECH / 256; ++j) {
        int e = base0 + j * 256;
        if (e < E) {
            int d = ed[e];
            int pos = atomicAdd(&cnt[d * 8 + xcc], 1);
            if (pos < SEGC) {
                csr[(long)d * ROW + xcc * SEGC + pos] = es[e];
            } else {
                int po = atomicAdd(&ovf[d], 1);
                if (po < OVFS) csr[(long)d * ROW + 8 * SEGC + po] = es[e];
            }
        }
    }
}

// ---------------------------------------------------------------------------
// Megafuse: [0,f1) fill1 | [f1,f2) convert x -> {x8 all rows, xb first 25k} |
// [f2,..) convert weights (transposed bf16, K-concat [self||neigh]).
// ---------------------------------------------------------------------------
__global__ void megafuse(const int* __restrict__ es1, const int* __restrict__ ed1,
                         int E1, int* __restrict__ cnt1, int* __restrict__ ovf1,
                         int* __restrict__ csr1,
                         const float* __restrict__ x, unsigned* __restrict__ xbu,
                         unsigned* __restrict__ x8u, long n4,
                         const float* __restrict__ Ws1, const float* __restrict__ Wn1,
                         const float* __restrict__ Ws2, const float* __restrict__ Wn2,
                         unsigned short* __restrict__ Wt1,
                         unsigned short* __restrict__ Wt2,
                         int f1, int f2) {
    const int b = blockIdx.x;
    const int tid = threadIdx.x;
    if (b < f1) {                       // fill layer 1
        fill_body(es1, ed1, E1, b * ECH + tid, cnt1, ovf1, csr1);
    } else if (b < f2) {                // convert x
        long i0 = (long)(b - f1) * 512 + tid;
#pragma unroll
        for (int j = 0; j < 2; ++j) {
            long i = i0 + j * 256;
            if (i < n4) {
                float4 v = reinterpret_cast<const float4*>(x)[i];
                int p = __builtin_amdgcn_cvt_pk_fp8_f32(v.x, v.y, 0, false);
                p = __builtin_amdgcn_cvt_pk_fp8_f32(v.z, v.w, p, true);
                x8u[i] = (unsigned)p;
                if (i < (long)SIZE1 * (D_IN / 4)) {   // rows < 25000
                    uint2 o;
                    o.x = pack_bf16(v.x, v.y);
                    o.y = pack_bf16(v.z, v.w);
                    reinterpret_cast<uint2*>(xbu)[i] = o;
                }
            }
        }
    } else {                            // convert weights
        int i = (b - f2) * 256 + tid;
        if (i < HID * (2 * D_IN)) {     // Wt1: 256 x 256
            int n = i >> 8, k = i & 255;
            float v = (k < D_IN) ? Ws1[k * HID + n] : Wn1[(k - D_IN) * HID + n];
            Wt1[i] = f32_to_bf16_rne(v);
        } else {
            int j = i - HID * (2 * D_IN);
            if (j < OUT_D * (2 * HID)) {  // Wt2: 64 x 512
                int n = j >> 9, k = j & 511;
                float v = (k < HID) ? Ws2[k * OUT_D + n] : Wn2[(k - HID) * OUT_D + n];
                Wt2[j] = f32_to_bf16_rne(v);
            }
        }
    }
}

// ---------------------------------------------------------------------------
// Pull-mean aggregation from fp8 rows, bf16 mean out, fp32 accumulate.
// Wave per dst; GL lanes/group (row = GL uint4 of fp8 = GL*16 values),
// NG = 64/GL groups; NR rounds x 8 predicated steps cover n <= 64 with all
// shfls at full wave activity (EXEC-safe; r9 lesson). Inactive steps load
// row 0 (clamped idx) and skip the add. Exact direct-read tail for n > 64.
// FUSE: trailing blocks run fill_body for layer 2.
// ---------------------------------------------------------------------------
template <int GL, bool FUSE>
__global__ void agg_pull6(const uint4* __restrict__ X4,
                          const int* __restrict__ csr,
                          const int* __restrict__ cnt,
                          const int* __restrict__ ovf,
                          uint4* __restrict__ meanOut, int ndst, int aggBlocks,
                          const int* __restrict__ esF, const int* __restrict__ edF,
                          int EF, int* __restrict__ cntF, int* __restrict__ ovfF,
                          int* __restrict__ csrF) {
    if (FUSE && (int)blockIdx.x >= aggBlocks) {
        fill_body(esF, edF, EF, ((int)blockIdx.x - aggBlocks) * ECH + threadIdx.x,
                  cntF, ovfF, csrF);
        return;
    }
    constexpr int NG = 64 / GL;                    // groups per wave
    constexpr int NR = (64 + NG * 8 - 1) / (NG * 8);  // rounds of 8 steps
    const int wid = threadIdx.x >> 6;
    const int lane = threadIdx.x & 63;
    const int d = blockIdx.x * 4 + wid;
    if (d >= ndst) return;   // wave-uniform (ndst divisible by 4)

    int myc = 0;
    if (lane < 8) myc = min(cnt[d * 8 + lane], SEGC);
    else if (lane == 8) myc = min(ovf[d], OVFS);
    int cum[10];
    cum[0] = 0;
#pragma unroll
    for (int k = 0; k < 9; ++k) cum[k + 1] = cum[k] + __shfl(myc, k);
    const int n = cum[9];
    const long rowb = (long)d * ROW;

    // lane = edge index: resolve slot once, fetch src idx into register
    int slot = lane;
#pragma unroll
    for (int t = 1; t < 9; ++t)
        if (lane >= cum[t]) slot = (t < 8 ? t * SEGC : 8 * SEGC) + (lane - cum[t]);
    int myidx = 0;
    if (lane < n) myidx = csr[rowb + slot];

    const int g = lane / GL;       // group id
    const int c = lane % GL;       // uint4 column within the fp8 row
    const int nmain = min(n, 64);

    float acc[16];
#pragma unroll
    for (int j = 0; j < 16; ++j) acc[j] = 0.0f;

#pragma unroll
    for (int r = 0; r < NR; ++r) {
        const int base = r * NG * 8;
        if (base < nmain) {        // wave-uniform guard
            int s[8];
            bool act[8];
#pragma unroll
            for (int t = 0; t < 8; ++t) {
                const int e = base + g + NG * t;
                int ss = __shfl(myidx, e & 63);   // full-activity shfl
                act[t] = (e < nmain);
                s[t] = act[t] ? ss : 0;           // clamp: harmless row-0 load
            }
            uint4 v[8];
#pragma unroll
            for (int t = 0; t < 8; ++t) v[t] = X4[(long)s[t] * GL + c];
#pragma unroll
            for (int t = 0; t < 8; ++t)
                if (act[t]) add16(acc, v[t]);
        }
    }
    // exact rare tail for n > 64: direct csr reads with per-edge slot chain
    for (int j2 = 64 + g; j2 < n; j2 += NG) {
        int sl = j2;
#pragma unroll
        for (int t = 1; t < 9; ++t)
            if (j2 >= cum[t]) sl = (t < 8 ? t * SEGC : 8 * SEGC) + (j2 - cum[t]);
        long s0 = csr[rowb + sl];
        uint4 v0 = X4[s0 * GL + c];
        add16(acc, v0);
    }
    // cross-group reduce
#pragma unroll
    for (int j = 0; j < 16; ++j) {
        if (GL == 8) acc[j] += __shfl_xor(acc[j], 8);
        acc[j] += __shfl_xor(acc[j], 16);
        acc[j] += __shfl_xor(acc[j], 32);
    }
    if (g == 0) {
        const float inv = 1.0f / (float)max(n, 1);
        uint4 o0, o1;
        o0.x = pack_bf16(acc[0] * inv, acc[1] * inv);
        o0.y = pack_bf16(acc[2] * inv, acc[3] * inv);
        o0.z = pack_bf16(acc[4] * inv, acc[5] * inv);
        o0.w = pack_bf16(acc[6] * inv, acc[7] * inv);
        o1.x = pack_bf16(acc[8] * inv, acc[9] * inv);
        o1.y = pack_bf16(acc[10] * inv, acc[11] * inv);
        o1.z = pack_bf16(acc[12] * inv, acc[13] * inv);
        o1.w = pack_bf16(acc[14] * inv, acc[15] * inv);
        meanOut[(long)d * (GL * 2) + c * 2]     = o0;  // mean row = GL*2 uint4
        meanOut[(long)d * (GL * 2) + c * 2 + 1] = o1;
    }
}

// ---------------------------------------------------------------------------
// Fused SAGE GEMM via MFMA (bf16 in, fp32 acc).
// C[i][n] = act(Aself[i][:]@Wt[n][0:KPH] + Amean[i][:]@Wt[n][KPH:2KPH] + b[n])
// 64x64 tile, 4 waves (2x2), wave does 32x32 via 2x2 16x16x32 frags.
// LDS XOR-swizzled for conflict-free ds_read_b128.
// H8: epilogue also writes fp8 copy (feeds layer-2 gather).
// LSM: fuse row log_softmax (BN=64 == full row) via LDS tile + shfl.
// ---------------------------------------------------------------------------
template <int KPH, bool RELU, bool OUT_BF16, bool LSM, bool H8>
__global__ __launch_bounds__(256) void sage_gemm_mfma(
    const unsigned short* __restrict__ Aself,
    const unsigned short* __restrict__ Amean,
    const unsigned short* __restrict__ Wt,
    const float* __restrict__ bias,
    void* __restrict__ Cout, unsigned char* __restrict__ H8out, int M, int N) {
    constexpr int BM = 64, BN = 64;
    constexpr int ITERS = (BM * KPH) / (256 * 8);
    __shared__ unsigned short As[BM * KPH];
    __shared__ unsigned short Bs[BN * KPH];

    const int tid = threadIdx.x;
    const int wid = tid >> 6;
    const int lane = tid & 63;
    const int wm = wid >> 1, wn = wid & 1;
    const int rowBase = blockIdx.x * BM;
    const int colBase = blockIdx.y * BN;

    f32x4 acc[2][2];
#pragma unroll
    for (int a = 0; a < 2; ++a)
#pragma unroll
        for (int b = 0; b < 2; ++b)
#pragma unroll
            for (int j = 0; j < 4; ++j) acc[a][b][j] = 0.0f;

#pragma unroll
    for (int p = 0; p < 2; ++p) {
        const unsigned short* __restrict__ A = p ? Amean : Aself;
        __syncthreads();
#pragma unroll
        for (int it = 0; it < ITERS; ++it) {
            int flat = (it * 256 + tid) * 8;
            int r = flat / KPH, kc = flat % KPH;
            int gr = rowBase + r;
            if (gr >= M) gr = M - 1;
            uint4 v = *reinterpret_cast<const uint4*>(&A[(long)gr * KPH + kc]);
            int idx = (r * KPH + kc) ^ ((r & 7) << 3);
            *reinterpret_cast<uint4*>(&As[idx]) = v;
        }
#pragma unroll
        for (int it = 0; it < ITERS; ++it) {
            int flat = (it * 256 + tid) * 8;
            int r = flat / KPH, kc = flat % KPH;
            uint4 v = *reinterpret_cast<const uint4*>(
                &Wt[(long)(colBase + r) * (2 * KPH) + p * KPH + kc]);
            int idx = (r * KPH + kc) ^ ((r & 7) << 3);
            *reinterpret_cast<uint4*>(&Bs[idx]) = v;
        }
        __syncthreads();
#pragma unroll
        for (int kk = 0; kk < KPH / 32; ++kk) {
            bf16x8 a[2], b[2];
            const int kb = kk * 32 + 8 * (lane >> 4);
#pragma unroll
            for (int f = 0; f < 2; ++f) {
                int r = wm * 32 + f * 16 + (lane & 15);
                int ia = (r * KPH + kb) ^ ((r & 7) << 3);
                a[f] = *reinterpret_cast<const bf16x8*>(&As[ia]);
                int rn = wn * 32 + f * 16 + (lane & 15);
                int ib = (rn * KPH + kb) ^ ((rn & 7) << 3);
                b[f] = *reinterpret_cast<const bf16x8*>(&Bs[ib]);
            }
#pragma unroll
            for (int fm = 0; fm < 2; ++fm)
#pragma unroll
                for (int fn = 0; fn < 2; ++fn)
                    acc[fm][fn] = __builtin_amdgcn_mfma_f32_16x16x32_bf16(
                        a[fm], b[fn], acc[fm][fn], 0, 0, 0);
        }
    }

    if (LSM) {
        float* sm = reinterpret_cast<float*>(As);  // 64x64 f32 = 16KB <= As
        __syncthreads();
#pragma unroll
        for (int fm = 0; fm < 2; ++fm)
#pragma unroll
            for (int fn = 0; fn < 2; ++fn) {
                int c = wn * 32 + fn * 16 + (lane & 15);
                float bv = bias[colBase + c];
#pragma unroll
                for (int j = 0; j < 4; ++j) {
                    int r = wm * 32 + fm * 16 + 4 * (lane >> 4) + j;
                    sm[r * BN + c] = acc[fm][fn][j] + bv;
                }
            }
        __syncthreads();
        for (int rr = 0; rr < 16; ++rr) {
            int r = wid * 16 + rr;
            int gr = rowBase + r;
            if (gr >= M) continue;
            float v = sm[r * BN + lane];
            float m = v;
#pragma unroll
            for (int o = 32; o; o >>= 1) m = fmaxf(m, __shfl_xor(m, o));
            float ex = __expf(v - m);
            float s = ex;
#pragma unroll
            for (int o = 32; o; o >>= 1) s += __shfl_xor(s, o);
            ((float*)Cout)[(long)gr * N + lane] = v - m - __logf(s);
        }
    } else {
#pragma unroll
        for (int fm = 0; fm < 2; ++fm) {
#pragma unroll
            for (int fn = 0; fn < 2; ++fn) {
                int gc = colBase + wn * 32 + fn * 16 + (lane & 15);
                float bv = bias[gc];
#pragma unroll
                for (int j = 0; j < 4; ++j) {
                    int gr = rowBase + wm * 32 + fm * 16 + 4 * (lane >> 4) + j;
                    if (gr < M) {
                        float v = acc[fm][fn][j] + bv;
                        if (RELU) v = fmaxf(v, 0.0f);
                        if (OUT_BF16)
                            ((unsigned short*)Cout)[(long)gr * N + gc] =
                                f32_to_bf16_rne(v);
                        else
                            ((float*)Cout)[(long)gr * N + gc] = v;
                        if (H8) {
                            int b8 = __builtin_amdgcn_cvt_pk_fp8_f32(v, v, 0, false);
                            H8out[(long)gr * N + gc] = (unsigned char)(b8 & 0xff);
                        }
                    }
                }
            }
        }
    }
}

// ---------------------------------------------------------------------------

extern "C" void kernel_launch(void* const* d_in, const int* in_sizes, int n_in,
                              void* d_out, int out_size, void* d_ws, size_t ws_size,
                              hipStream_t stream) {
    const float* x       = (const float*)d_in[0];
    const float* Wself1  = (const float*)d_in[1];
    const float* Wneigh1 = (const float*)d_in[2];
    const float* b1      = (const float*)d_in[3];
    const float* Wself2  = (const float*)d_in[4];
    const float* Wneigh2 = (const float*)d_in[5];
    const float* b2      = (const float*)d_in[6];
    const int* es1 = (const int*)d_in[7];
    const int* ed1 = (const int*)d_in[8];
    const int* es2 = (const int*)d_in[9];
    const int* ed2 = (const int*)d_in[10];
    const int E1 = in_sizes[7];
    const int E2 = in_sizes[9];
    const long NSRC = in_sizes[0] / D_IN;  // 100000

    // ---- workspace layout ----
    // ints: [cnt1:S1*8][ovf1:S1][cnt2:S2*8][ovf2:S2] (memset 270000 ints)
    //       [csr2: S2*ROW][csr1: S1*ROW]  (h1 overlays csr1 after agg1)
    // then: [xb: 25k x 128 bf16][x8: 100k x 128 u8][Wt1][Wt2]
    //       [mean1: 25k x 128 bf16][h8: 25k x 256 u8]
    // overlays: mean2 -> xb region (xb dead after gemm1)
    int* cnt1 = (int*)d_ws;                          // SIZE1*8
    int* ovf1 = cnt1 + (size_t)SIZE1 * 8;            // SIZE1
    int* cnt2 = ovf1 + SIZE1;                        // SIZE2*8
    int* ovf2 = cnt2 + (size_t)SIZE2 * 8;            // SIZE2
    int* csr2 = ovf2 + SIZE2;                        // SIZE2*ROW
    int* csr1 = csr2 + (size_t)SIZE2 * ROW;          // SIZE1*ROW
    const size_t zero_ints = (size_t)SIZE1 * 9 + (size_t)SIZE2 * 9;  // 270000
    const size_t int_elems = zero_ints + (size_t)SIZE2 * ROW + (size_t)SIZE1 * ROW;
    unsigned short* xb  = (unsigned short*)((int*)d_ws + int_elems);  // 25k*128
    unsigned short* mean2 = xb;                       // overlay (xb dead by agg2)
    unsigned char* x8   = (unsigned char*)(xb + (size_t)SIZE1 * D_IN);  // 100k*128
    unsigned short* Wt1 = (unsigned short*)(x8 + NSRC * D_IN);  // 256*256
    unsigned short* Wt2 = Wt1 + (size_t)HID * (2 * D_IN);       // 64*512
    unsigned short* mean1 = Wt2 + (size_t)OUT_D * (2 * HID);    // 25k*128
    unsigned char* h8   = (unsigned char*)(mean1 + (size_t)SIZE1 * D_IN);  // 25k*256
    unsigned short* h1  = (unsigned short*)csr1;     // overlay (csr1 dead by gemm1)

    hipMemsetAsync(d_ws, 0, zero_ints * sizeof(int), stream);

    // ---- megafuse: fill1 + conversions ----
    const long n4 = NSRC * D_IN / 4;                 // float4 groups in x
    const int f1 = (E1 + ECH - 1) / ECH;             // 391
    const int f2 = f1 + (int)((n4 + 511) / 512);
    const int nb_cw = (HID * (2 * D_IN) + OUT_D * (2 * HID) + 255) / 256;
    megafuse<<<f2 + nb_cw, 256, 0, stream>>>(
        es1, ed1, E1, cnt1, ovf1, csr1,
        x, (unsigned*)xb, (unsigned*)x8, n4,
        Wself1, Wneigh1, Wself2, Wneigh2, Wt1, Wt2, f1, f2);

    // ---- layer 1: fp8 pull-mean (+ fused fill2) + GEMM(relu, bf16+fp8 out)
    {
        const int aggB = (SIZE1 + 3) / 4;            // 6250
        const int fillB = (E2 + ECH - 1) / ECH;      // 79
        agg_pull6<8, true><<<aggB + fillB, 256, 0, stream>>>(
            (const uint4*)x8, csr1, cnt1, ovf1, (uint4*)mean1, SIZE1, aggB,
            es2, ed2, E2, cnt2, ovf2, csr2);
    }
    {
        dim3 grid((SIZE1 + 63) / 64, HID / 64);
        sage_gemm_mfma<D_IN, true, true, false, true><<<grid, 256, 0, stream>>>(
            xb, mean1, Wt1, b1, h1, h8, SIZE1, HID);
    }

    // ---- layer 2: fp8 pull-mean + GEMM(+fused log_softmax, f32 out) ----
    agg_pull6<16, false><<<(SIZE2 + 3) / 4, 256, 0, stream>>>(
        (const uint4*)h8, csr2, cnt2, ovf2, (uint4*)mean2, SIZE2, 1 << 30,
        nullptr, nullptr, 0, nullptr, nullptr, nullptr);
    {
        dim3 grid((SIZE2 + 63) / 64, OUT_D / 64);
        sage_gemm_mfma<HID, false, false, true, false><<<grid, 256, 0, stream>>>(
            h1, mean2, Wt2, b2, d_out, nullptr, SIZE2, OUT_D);
    }
}